// Round 3
// baseline (2126.750 us; speedup 1.0000x reference)
//
#include <hip/hip_runtime.h>
#include <hip/hip_bf16.h>

// COLT graph propagation, MI355X (gfx950).
// ABI dtypes: ALL float tensors are fp32 (per reference jnp.float32 — round-2
// NaN was caused by misreading fp32 as bf16), indices int32, output fp32.
// Structure: per-launch on-device CSR build (hist -> 1-block scan -> cursor
// scatter, dropped edges filtered), then one-wave-per-row gather SpMM fused
// with l2norm + fp32 accumulate into d_out. Layer-1 intermediate F1 and the
// scene-feature copy S16 are bf16 internally (2^-9 rel err << 0.114 thresh)
// to keep ws ~116 MB. /(i+2) scalings dropped: linear propagation + scale-
// invariant l2norm -> exact cancellation.

#define DD 384
#define KK 6              // DD / 64
typedef __hip_bfloat16 bf16;

__device__ __forceinline__ float b2f(bf16 x) { return __bfloat162float(x); }

// ---------------- CSR build ----------------

__global__ void hist_kernel(const int* __restrict__ rows, const float* __restrict__ vals,
                            int* __restrict__ cnt, int nnz, int filter)
{
    int e = blockIdx.x * blockDim.x + threadIdx.x;
    if (e >= nnz) return;
    if (filter && vals[e] == 0.0f) return;
    atomicAdd(&cnt[rows[e]], 1);
}

// exclusive scan of cnt[0..n) into ptr[0..n], single block of 1024.
__global__ void exscan_kernel(const int* __restrict__ cnt, int* __restrict__ ptr, int n)
{
    __shared__ int tmp[1024];
    __shared__ int carry_s;
    int tid = threadIdx.x;
    if (tid == 0) carry_s = 0;
    __syncthreads();
    for (int base = 0; base < n; base += 1024) {
        int i = base + tid;
        int v = (i < n) ? cnt[i] : 0;
        tmp[tid] = v;
        __syncthreads();
        for (int off = 1; off < 1024; off <<= 1) {
            int add = (tid >= off) ? tmp[tid - off] : 0;
            __syncthreads();
            tmp[tid] += add;
            __syncthreads();
        }
        int incl = tmp[tid];
        int tile_sum = tmp[1023];
        int carry = carry_s;
        if (i < n) ptr[i] = carry + incl - v;   // exclusive
        __syncthreads();
        if (tid == 0) carry_s = carry + tile_sum;
        __syncthreads();
    }
    if (tid == 0) ptr[n] = carry_s;
}

__global__ void scatter_kernel(const int* __restrict__ rows, const int* __restrict__ cols,
                               const float* __restrict__ vals, const float* __restrict__ vals2,
                               int* __restrict__ cur, int* __restrict__ scol,
                               float* __restrict__ sval, float* __restrict__ sval2,
                               int nnz, int filter)
{
    int e = blockIdx.x * blockDim.x + threadIdx.x;
    if (e >= nnz) return;
    float v = vals[e];
    if (filter && v == 0.0f) return;
    int pos = atomicAdd(&cur[rows[e]], 1);
    scol[pos] = cols[e];
    sval[pos] = v;
    if (sval2) sval2[pos] = vals2[e];
}

// ---------------- fused gather SpMM ----------------

template <bool X16>
__device__ __forceinline__ float ld_src(const void* p, size_t i)
{
    if (X16) return b2f(((const bf16*)p)[i]);
    else     return ((const float*)p)[i];
}

// One 64-lane wave per row. f[row] = sum_e v_e * src[col_e]; then
// acc[row] += f / max(||f||, 1e-12) (fp32 RMW, wave-exclusive);
// optionally store bf16(f) for the next layer.
template <bool A16, bool B16>
__global__ void gather_norm_acc(const int* __restrict__ ptr, const int* __restrict__ scol,
                                const float* __restrict__ sval,
                                const void* __restrict__ srcA, const void* __restrict__ srcB,
                                int nsplit,
                                float* __restrict__ acc, bf16* __restrict__ store, int nrows)
{
    long tid = (long)blockIdx.x * blockDim.x + threadIdx.x;
    int row = (int)(tid >> 6);
    if (row >= nrows) return;
    int lane = threadIdx.x & 63;
    int e0 = ptr[row], e1 = ptr[row + 1];
    float f[KK] = {0.f, 0.f, 0.f, 0.f, 0.f, 0.f};
    for (int e = e0; e < e1; ++e) {
        float v = sval[e];
        int c = scol[e];
        if (c < nsplit) {
            size_t base = (size_t)c * DD;
#pragma unroll
            for (int k = 0; k < KK; ++k) f[k] += v * ld_src<A16>(srcA, base + lane + (k << 6));
        } else {
            size_t base = (size_t)(c - nsplit) * DD;
#pragma unroll
            for (int k = 0; k < KK; ++k) f[k] += v * ld_src<B16>(srcB, base + lane + (k << 6));
        }
    }
    float ss = 0.f;
#pragma unroll
    for (int k = 0; k < KK; ++k) ss += f[k] * f[k];
#pragma unroll
    for (int off = 32; off > 0; off >>= 1) ss += __shfl_xor(ss, off, 64);
    float scale = 1.0f / fmaxf(sqrtf(ss), 1e-12f);
    float* __restrict__ ar = acc + (size_t)row * DD;
#pragma unroll
    for (int k = 0; k < KK; ++k) {
        int j = lane + (k << 6);
        ar[j] = ar[j] + f[k] * scale;
        if (store) store[(size_t)row * DD + j] = __float2bfloat16(f[k]);
    }
}

// Plain gather SpMM -> fp32 dst (and optional bf16 dst2). One wave per row.
template <bool SRC16>
__global__ void gather_plain(const int* __restrict__ ptr, const int* __restrict__ scol,
                             const float* __restrict__ sval,
                             const void* __restrict__ src,
                             float* __restrict__ dst, bf16* __restrict__ dst2, int nrows)
{
    long tid = (long)blockIdx.x * blockDim.x + threadIdx.x;
    int row = (int)(tid >> 6);
    if (row >= nrows) return;
    int lane = threadIdx.x & 63;
    int e0 = ptr[row], e1 = ptr[row + 1];
    float f[KK] = {0.f, 0.f, 0.f, 0.f, 0.f, 0.f};
    for (int e = e0; e < e1; ++e) {
        float v = sval[e];
        size_t base = (size_t)scol[e] * DD;
#pragma unroll
        for (int k = 0; k < KK; ++k) f[k] += v * ld_src<SRC16>(src, base + lane + (k << 6));
    }
#pragma unroll
    for (int k = 0; k < KK; ++k) {
        int j = lane + (k << 6);
        dst[(size_t)row * DD + j] = f[k];
        if (dst2) dst2[(size_t)row * DD + j] = __float2bfloat16(f[k]);
    }
}

static inline unsigned gridw(long threads) { return (unsigned)((threads + 255) / 256); }

extern "C" void kernel_launch(void* const* d_in, const int* in_sizes, int n_in,
                              void* d_out, int out_size, void* d_ws, size_t ws_size,
                              hipStream_t stream)
{
    const int NQ = 100000, NT = 20000, NS = 10000;
    const int N1 = NQ + NT;        // queries+tools
    const int N2 = NQ + NS;        // queries+scenes

    const float* q     = (const float*)d_in[0];
    const float* t     = (const float*)d_in[1];
    const float* tlv   = (const float*)d_in[2];
    const float* slv   = (const float*)d_in[3];
    const float* aggv  = (const float*)d_in[4];
    const float* aggov = (const float*)d_in[5];
    const int* tlr  = (const int*)d_in[6];
    const int* tlc  = (const int*)d_in[7];
    const int* slr  = (const int*)d_in[8];
    const int* slc  = (const int*)d_in[9];
    const int* aggr = (const int*)d_in[10];
    const int* aggc = (const int*)d_in[11];
    const int tl_nnz  = in_sizes[6];
    const int sl_nnz  = in_sizes[8];
    const int agg_nnz = in_sizes[10];

    // ---- workspace carve (bump allocator, 16B aligned) ----
    char* w = (char*)d_ws;
    size_t off = 0;
    auto alloc = [&](size_t bytes) -> void* {
        void* p = w + off;
        off += (bytes + 15) & ~(size_t)15;
        return p;
    };
    bf16*  F1     = (bf16*) alloc((size_t)N1 * DD * sizeof(bf16));   // layer-1 feats (bf16 internal)
    bf16*  S16    = (bf16*) alloc((size_t)NS * DD * sizeof(bf16));   // scene feats copy
    int*   tl_ptr = (int*)  alloc((size_t)(N1 + 1) * sizeof(int));
    int*   tl_cur = (int*)  alloc((size_t)(N1 + 1) * sizeof(int));
    int*   sl_ptr = (int*)  alloc((size_t)(N2 + 1) * sizeof(int));
    int*   sl_cur = (int*)  alloc((size_t)(N2 + 1) * sizeof(int));
    int*   ag_ptr = (int*)  alloc((size_t)(NS + 1) * sizeof(int));
    int*   ag_cur = (int*)  alloc((size_t)(NS + 1) * sizeof(int));
    int*   tl_col = (int*)  alloc((size_t)tl_nnz * sizeof(int));
    float* tl_val = (float*)alloc((size_t)tl_nnz * sizeof(float));
    int*   sl_col = (int*)  alloc((size_t)sl_nnz * sizeof(int));
    float* sl_val = (float*)alloc((size_t)sl_nnz * sizeof(float));
    int*   ag_col = (int*)  alloc((size_t)agg_nnz * sizeof(int));
    float* ag_val = (float*)alloc((size_t)agg_nnz * sizeof(float));  // ED-dropped
    float* ago_val= (float*)alloc((size_t)agg_nnz * sizeof(float));  // original
    // total ~116 MB

    // ---- output carve (fp32, element offsets) ----
    float* out = (float*)d_out;
    float* TL  = out;                                  // TL_q | TL_t  (N1*D)
    float* TLt = TL + (size_t)NQ * DD;
    float* TLs = out + (size_t)N1 * DD;                // TL_s (NS*D)
    float* SL  = TLs + (size_t)NS * DD;                // SL_q | SL_s  (N2*D)
    float* SLs = SL + (size_t)NQ * DD;

    // ---- CSR builds ----
    hipMemsetAsync(tl_cur, 0, (size_t)(N1 + 1) * sizeof(int), stream);
    hist_kernel<<<gridw(tl_nnz), 256, 0, stream>>>(tlr, tlv, tl_cur, tl_nnz, 1);
    exscan_kernel<<<1, 1024, 0, stream>>>(tl_cur, tl_ptr, N1);
    hipMemcpyAsync(tl_cur, tl_ptr, (size_t)(N1 + 1) * sizeof(int), hipMemcpyDeviceToDevice, stream);
    scatter_kernel<<<gridw(tl_nnz), 256, 0, stream>>>(tlr, tlc, tlv, nullptr,
                                                      tl_cur, tl_col, tl_val, nullptr, tl_nnz, 1);

    hipMemsetAsync(sl_cur, 0, (size_t)(N2 + 1) * sizeof(int), stream);
    hist_kernel<<<gridw(sl_nnz), 256, 0, stream>>>(slr, slv, sl_cur, sl_nnz, 1);
    exscan_kernel<<<1, 1024, 0, stream>>>(sl_cur, sl_ptr, N2);
    hipMemcpyAsync(sl_cur, sl_ptr, (size_t)(N2 + 1) * sizeof(int), hipMemcpyDeviceToDevice, stream);
    scatter_kernel<<<gridw(sl_nnz), 256, 0, stream>>>(slr, slc, slv, nullptr,
                                                      sl_cur, sl_col, sl_val, nullptr, sl_nnz, 1);

    hipMemsetAsync(ag_cur, 0, (size_t)(NS + 1) * sizeof(int), stream);
    hist_kernel<<<gridw(agg_nnz), 256, 0, stream>>>(aggr, aggv, ag_cur, agg_nnz, 0);
    exscan_kernel<<<1, 1024, 0, stream>>>(ag_cur, ag_ptr, NS);
    hipMemcpyAsync(ag_cur, ag_ptr, (size_t)(NS + 1) * sizeof(int), hipMemcpyDeviceToDevice, stream);
    scatter_kernel<<<gridw(agg_nnz), 256, 0, stream>>>(aggr, aggc, aggv, aggov,
                                                       ag_cur, ag_col, ag_val, ago_val, agg_nnz, 0);

    const size_t qB = (size_t)NQ * DD * sizeof(float);
    const size_t tB = (size_t)NT * DD * sizeof(float);
    const int BIG = 0x7fffffff;

    // ---- TL propagate over queries+tools ----
    hipMemcpyAsync(TL, q, qB, hipMemcpyDeviceToDevice, stream);    // acc layer-0
    hipMemcpyAsync(TLt, t, tB, hipMemcpyDeviceToDevice, stream);
    gather_norm_acc<false, false><<<gridw((long)N1 * 64), 256, 0, stream>>>(
        tl_ptr, tl_col, tl_val, q, t, NQ, TL, F1, N1);
    gather_norm_acc<true, true><<<gridw((long)N1 * 64), 256, 0, stream>>>(
        tl_ptr, tl_col, tl_val, F1, F1, BIG, TL, nullptr, N1);

    // ---- TL_s = agg(dropped) @ TL_t ----
    gather_plain<false><<<gridw((long)NS * 64), 256, 0, stream>>>(
        ag_ptr, ag_col, ag_val, TLt, TLs, nullptr, NS);

    // ---- S = aggo @ t -> SLs (fp32 acc layer-0) + S16 (bf16 gather source) ----
    gather_plain<false><<<gridw((long)NS * 64), 256, 0, stream>>>(
        ag_ptr, ag_col, ago_val, t, SLs, S16, NS);

    // ---- SL propagate over queries+scenes ----
    hipMemcpyAsync(SL, q, qB, hipMemcpyDeviceToDevice, stream);    // acc layer-0 (queries)
    gather_norm_acc<false, true><<<gridw((long)N2 * 64), 256, 0, stream>>>(
        sl_ptr, sl_col, sl_val, q, S16, NQ, SL, F1, N2);
    gather_norm_acc<true, true><<<gridw((long)N2 * 64), 256, 0, stream>>>(
        sl_ptr, sl_col, sl_val, F1, F1, BIG, SL, nullptr, N2);
}